// Round 5
// baseline (1397.719 us; speedup 1.0000x reference)
//
#include <hip/hip_runtime.h>
#include <stdint.h>

// ---------- types ----------
typedef __bf16 bf16x8 __attribute__((ext_vector_type(8)));
typedef float f32x4 __attribute__((ext_vector_type(4)));
typedef unsigned short u16x4 __attribute__((ext_vector_type(4)));

static __device__ __forceinline__ unsigned short f2bf(float f) {
    union { float f; unsigned u; } v; v.f = f;
    unsigned r = (v.u + 0x7FFFu + ((v.u >> 16) & 1u)) >> 16;  // RNE
    return (unsigned short)r;
}

// ---------- lean grid barrier: monotonic counter, 1 atomic/block ----------
__device__ __forceinline__ void gbar(unsigned* ctr, unsigned target) {
    __syncthreads();
    if (threadIdx.x == 0) {
        __threadfence();  // release our writes device-scope (L2 wb)
        __hip_atomic_fetch_add(ctr, 1u, __ATOMIC_RELEASE, __HIP_MEMORY_SCOPE_AGENT);
        while (__hip_atomic_load(ctr, __ATOMIC_ACQUIRE, __HIP_MEMORY_SCOPE_AGENT) < target)
            __builtin_amdgcn_s_sleep(2);
        __threadfence();  // acquire others' writes
    }
    __syncthreads();
}

// ---------- GEMM tile: D[m][n] = sum_k A[m*LDA+k]*B[n*LDB+k]; out[n*LDO+m] ----
// 128x64 tile, BK=64, 256 threads (4 waves 2x2: 64m x 32n per wave).
// LDS XOR swizzle: chunk(row,pos) at row*8 + (pos ^ (row&7)), 16B chunks.
template<bool BIAS, bool RELU, typename OT>
__device__ __forceinline__
void gemm_tile(const unsigned short* __restrict__ A, int LDA,
               const unsigned short* __restrict__ B, int LDB,
               OT* __restrict__ out, int LDO,
               const float* __restrict__ bias,
               int m0, int n0,
               unsigned short* As, unsigned short* Bs) {
    const int tid  = threadIdx.x;
    const int lane = tid & 63;
    const int wave = tid >> 6;
    const int quad = lane >> 4;
    const int l16  = lane & 15;
    const int wm   = wave & 1;
    const int wn   = wave >> 1;

    const int srow = tid >> 3;                 // 0..31
    const int spos = (tid & 7) ^ (srow & 7);
    const unsigned short* aG = A + (size_t)(m0 + srow) * LDA + spos * 8;
    const unsigned short* bG = B + (size_t)(n0 + srow) * LDB + spos * 8;
    char* aL = (char*)As + tid * 16;
    char* bL = (char*)Bs + tid * 16;

    f32x4 acc[4][2];
    #pragma unroll
    for (int i = 0; i < 4; ++i)
        #pragma unroll
        for (int j = 0; j < 2; ++j) {
            f32x4 z = {0.f, 0.f, 0.f, 0.f};
            acc[i][j] = z;
        }

    #pragma unroll 1
    for (int kk = 0; kk < 8; ++kk) {   // K=512, BK=64
        const int ko = kk * 64;
        #pragma unroll
        for (int r = 0; r < 4; ++r)
            __builtin_amdgcn_global_load_lds(
                (__attribute__((address_space(1))) void*)(uintptr_t)(aG + (size_t)(r * 32) * LDA + ko),
                (__attribute__((address_space(3))) void*)(aL + r * 4096), 16, 0, 0);
        #pragma unroll
        for (int r = 0; r < 2; ++r)
            __builtin_amdgcn_global_load_lds(
                (__attribute__((address_space(1))) void*)(uintptr_t)(bG + (size_t)(r * 32) * LDB + ko),
                (__attribute__((address_space(3))) void*)(bL + r * 4096), 16, 0, 0);
        __syncthreads();

        #pragma unroll
        for (int ks = 0; ks < 2; ++ks) {
            bf16x8 af[4], bfr[2];
            #pragma unroll
            for (int i = 0; i < 4; ++i) {
                const int row = wm * 64 + i * 16 + l16;
                const int idx = row * 8 + ((ks * 4 + quad) ^ (row & 7));
                af[i] = *(const bf16x8*)((const char*)As + idx * 16);
            }
            #pragma unroll
            for (int j = 0; j < 2; ++j) {
                const int row = wn * 32 + j * 16 + l16;
                const int idx = row * 8 + ((ks * 4 + quad) ^ (row & 7));
                bfr[j] = *(const bf16x8*)((const char*)Bs + idx * 16);
            }
            #pragma unroll
            for (int i = 0; i < 4; ++i)
                #pragma unroll
                for (int j = 0; j < 2; ++j)
                    acc[i][j] = __builtin_amdgcn_mfma_f32_16x16x32_bf16(af[i], bfr[j], acc[i][j], 0, 0, 0);
        }
        __syncthreads();
    }

    #pragma unroll
    for (int i = 0; i < 4; ++i) {
        const int mb = m0 + wm * 64 + i * 16 + quad * 4;
        f32x4 bb = {0.f, 0.f, 0.f, 0.f};
        if constexpr (BIAS) bb = *(const f32x4*)(bias + mb);
        #pragma unroll
        for (int j = 0; j < 2; ++j) {
            const int n = n0 + wn * 32 + j * 16 + l16;
            f32x4 v = acc[i][j];
            if constexpr (BIAS) v += bb;
            if constexpr (RELU) {
                v.x = v.x > 0.f ? v.x : 0.f;
                v.y = v.y > 0.f ? v.y : 0.f;
                v.z = v.z > 0.f ? v.z : 0.f;
                v.w = v.w > 0.f ? v.w : 0.f;
            }
            if constexpr (sizeof(OT) == 4) {
                *(f32x4*)((float*)out + (size_t)n * LDO + mb) = v;
            } else {
                u16x4 o;
                o.x = f2bf(v.x); o.y = f2bf(v.y); o.z = f2bf(v.z); o.w = f2bf(v.w);
                *(u16x4*)((unsigned short*)out + (size_t)n * LDO + mb) = o;
            }
        }
    }
}

// ---- XCD-swizzled tile decode. blockIdx -> XCD is round-robin (bid % 8). ----
// Feature phase (1024 tiles = 128 m x 8 n): XCD k owns m-tiles [16k,16k+16).
__device__ __forceinline__ void feat_tile(int b, int& m0, int& n0) {
    const int xcd = b & 7, s = b >> 3;         // s in [0,128)
    m0 = (xcd * 16 + (s >> 3)) * 128;          // m-tile in [0,128)
    n0 = (s & 7) * 64;
}
// Aggregate phase (1024 tiles = 32 z x 4 m x 8 n): XCD k owns graphs {k,k+8,k+16,k+24}.
__device__ __forceinline__ void aggr_tile(int b, int& z, int& m0, int& n0) {
    const int xcd = b & 7, s = b >> 3;         // s in [0,128)
    z = xcd + 8 * (s >> 5);                    // 4 graphs per XCD
    const int inner = s & 31;
    m0 = (inner >> 3) * 128;                   // feat block in [0,512)
    n0 = (inner & 7) * 64;                     // node block
}

// ---------- fused kernel: prep + 6 GEMM phases, hand-rolled global barriers ----
// 1024 blocks x 256 threads, 4 blocks/CU (all co-resident; cooperative launch).
__global__ __launch_bounds__(256, 4)
void fused_gcn2(const float* __restrict__ X, const float* __restrict__ adj,
                const float* __restrict__ W0, const float* __restrict__ b0,
                const float* __restrict__ W1, const float* __restrict__ b1,
                const float* __restrict__ W2, const float* __restrict__ b2,
                float* __restrict__ out,
                unsigned short* __restrict__ bufH,
                unsigned short* __restrict__ adjB,
                unsigned short* __restrict__ tmpT,
                unsigned short* __restrict__ Wt,
                unsigned* __restrict__ ctr) {
    __shared__ unsigned short As[128 * 64];   // 16 KB
    __shared__ unsigned short Bs[64 * 64];    //  8 KB
    const int b = blockIdx.x;

    // ---- phase 0: transpose W0..W2 (768 blocks), convert X/adj (all blocks) ----
    if (b < 768) {
        float (*tileS)[33] = (float(*)[33])As;   // scratch overlay
        const int z = b >> 8, tile = b & 255;
        const float* W = (z == 0) ? W0 : (z == 1) ? W1 : W2;
        unsigned short* dst = Wt + (size_t)z * (512 * 512);
        const int bx = (tile & 15) * 32, by = (tile >> 4) * 32;
        const int tx = threadIdx.x & 31, ty = threadIdx.x >> 5;  // 32 x 8
        #pragma unroll
        for (int r = 0; r < 32; r += 8)
            tileS[ty + r][tx] = W[(size_t)(by + ty + r) * 512 + (bx + tx)];
        __syncthreads();
        #pragma unroll
        for (int r = 0; r < 32; r += 8)
            dst[(size_t)(bx + ty + r) * 512 + (by + tx)] = f2bf(tileS[tx][ty + r]);
    }
    {
        const int gt = b * 256 + threadIdx.x;   // 0..262143
        #pragma unroll 2
        for (int it = 0; it < 8; ++it) {
            const int i = it * 262144 + gt;
            f32x4 v = ((const f32x4*)X)[i];
            f32x4 w = ((const f32x4*)adj)[i];
            u16x4 o, p;
            o.x = f2bf(v.x); o.y = f2bf(v.y); o.z = f2bf(v.z); o.w = f2bf(v.w);
            p.x = f2bf(w.x); p.y = f2bf(w.y); p.z = f2bf(w.z); p.w = f2bf(w.w);
            ((u16x4*)bufH)[i] = o;
            ((u16x4*)adjB)[i] = p;
        }
    }
    gbar(ctr, 1024);

    int z, m0, n0;
    // ---- layer 0 ----
    feat_tile(b, m0, n0);
    gemm_tile<false, false, unsigned short>(bufH, 512, Wt, 512, tmpT, 16384,
                                            nullptr, m0, n0, As, Bs);
    gbar(ctr, 2048);
    aggr_tile(b, z, m0, n0);
    gemm_tile<true, true, unsigned short>(tmpT + z * 512, 16384,
                                          adjB + (size_t)z * 262144, 512,
                                          bufH + (size_t)z * 262144, 512,
                                          b0, m0, n0, As, Bs);
    gbar(ctr, 3072);
    // ---- layer 1 ----
    feat_tile(b, m0, n0);
    gemm_tile<false, false, unsigned short>(bufH, 512, Wt + 262144, 512, tmpT, 16384,
                                            nullptr, m0, n0, As, Bs);
    gbar(ctr, 4096);
    aggr_tile(b, z, m0, n0);
    gemm_tile<true, true, unsigned short>(tmpT + z * 512, 16384,
                                          adjB + (size_t)z * 262144, 512,
                                          bufH + (size_t)z * 262144, 512,
                                          b1, m0, n0, As, Bs);
    gbar(ctr, 5120);
    // ---- layer 2 (no relu, fp32 out) ----
    feat_tile(b, m0, n0);
    gemm_tile<false, false, unsigned short>(bufH, 512, Wt + 2 * 262144, 512, tmpT, 16384,
                                            nullptr, m0, n0, As, Bs);
    gbar(ctr, 6144);
    aggr_tile(b, z, m0, n0);
    gemm_tile<true, false, float>(tmpT + z * 512, 16384,
                                  adjB + (size_t)z * 262144, 512,
                                  out + (size_t)z * 262144, 512,
                                  b2, m0, n0, As, Bs);
}

// ================= fallback path (R2 structure) =================
__global__ void prep_kernel(const float* __restrict__ X,
                            const float* __restrict__ adj,
                            const float* __restrict__ W0,
                            const float* __restrict__ W1,
                            const float* __restrict__ W2,
                            unsigned short* __restrict__ bufH,
                            unsigned short* __restrict__ adjB,
                            unsigned short* __restrict__ Wt) {
    const int bid = blockIdx.x;
    const int t = threadIdx.x;
    if (bid < 16384) {
        const float* src = (bid < 8192) ? X : adj;
        unsigned short* dst = (bid < 8192) ? bufH : adjB;
        const int i = (bid & 8191) * 256 + t;
        f32x4 v = ((const f32x4*)src)[i];
        u16x4 o;
        o.x = f2bf(v.x); o.y = f2bf(v.y); o.z = f2bf(v.z); o.w = f2bf(v.w);
        ((u16x4*)dst)[i] = o;
    } else {
        const int wb = bid - 16384;
        const int z = wb >> 8;
        const int tile = wb & 255;
        const float* W = (z == 0) ? W0 : (z == 1) ? W1 : W2;
        unsigned short* dst = Wt + (size_t)z * (512 * 512);
        __shared__ float tileS[32][33];
        const int bx = (tile & 15) * 32, by = (tile >> 4) * 32;
        const int tx = t & 31, ty = t >> 5;
        #pragma unroll
        for (int r = 0; r < 32; r += 8)
            tileS[ty + r][tx] = W[(size_t)(by + ty + r) * 512 + (bx + tx)];
        __syncthreads();
        #pragma unroll
        for (int r = 0; r < 32; r += 8)
            dst[(size_t)(bx + ty + r) * 512 + (by + tx)] = f2bf(tileS[tx][ty + r]);
    }
}

template<bool FEAT, bool BIAS, bool RELU, typename OT>
__global__ __launch_bounds__(256, 4)
void gemm_swz(const unsigned short* __restrict__ A, int LDA,
              const unsigned short* __restrict__ B,
              OT* __restrict__ out, int LDO,
              const float* __restrict__ bias) {
    __shared__ unsigned short As[128 * 64];
    __shared__ unsigned short Bs[64 * 64];
    int z, m0, n0;
    if constexpr (FEAT) {
        feat_tile(blockIdx.x, m0, n0);
        gemm_tile<BIAS, RELU, OT>(A, LDA, B, 512, out, LDO, bias, m0, n0, As, Bs);
    } else {
        aggr_tile(blockIdx.x, z, m0, n0);
        gemm_tile<BIAS, RELU, OT>(A + z * 512, LDA, B + (size_t)z * 262144, 512,
                                  out + (size_t)z * 262144, LDO, bias, m0, n0, As, Bs);
    }
}

extern "C" void kernel_launch(void* const* d_in, const int* in_sizes, int n_in,
                              void* d_out, int out_size, void* d_ws, size_t ws_size,
                              hipStream_t stream) {
    (void)in_sizes; (void)n_in; (void)out_size; (void)ws_size;
    const float* X   = (const float*)d_in[0];
    const float* adj = (const float*)d_in[1];
    const float* W0  = (const float*)d_in[2];
    const float* b0  = (const float*)d_in[3];
    const float* W1  = (const float*)d_in[4];
    const float* b1  = (const float*)d_in[5];
    const float* W2  = (const float*)d_in[6];
    const float* b2  = (const float*)d_in[7];
    float* out = (float*)d_out;

    char* ws = (char*)d_ws;
    const size_t SZ = 16777216;  // 32*512*512*2
    unsigned short* adjB = (unsigned short*)(ws);
    unsigned short* bufH = (unsigned short*)(ws + SZ);
    unsigned short* tmpT = (unsigned short*)(ws + 2 * SZ);
    unsigned short* Wt   = (unsigned short*)(ws + 3 * SZ);
    unsigned* ctr        = (unsigned*)(ws + ((size_t)80 << 20));

    hipMemsetAsync(ctr, 0, 64, stream);   // barrier counter init (capture-safe)

    void* args[] = {(void*)&X, (void*)&adj, (void*)&W0, (void*)&b0,
                    (void*)&W1, (void*)&b1, (void*)&W2, (void*)&b2,
                    (void*)&out, (void*)&bufH, (void*)&adjB, (void*)&tmpT,
                    (void*)&Wt, (void*)&ctr};
    hipError_t err = hipLaunchCooperativeKernel((const void*)fused_gcn2,
                                                dim3(1024), dim3(256), args, 0, stream);
    if (err == hipSuccess) return;

    // fallback: multi-dispatch, same swizzled tiles
    prep_kernel<<<16384 + 768, 256, 0, stream>>>(X, adj, W0, W1, W2, bufH, adjB, Wt);
    gemm_swz<true, false, false, unsigned short>
        <<<1024, 256, 0, stream>>>(bufH, 512, Wt, tmpT, 16384, nullptr);
    gemm_swz<false, true, true, unsigned short>
        <<<1024, 256, 0, stream>>>(tmpT, 16384, adjB, bufH, 512, b0);
    gemm_swz<true, false, false, unsigned short>
        <<<1024, 256, 0, stream>>>(bufH, 512, Wt + 262144, tmpT, 16384, nullptr);
    gemm_swz<false, true, true, unsigned short>
        <<<1024, 256, 0, stream>>>(tmpT, 16384, adjB, bufH, 512, b1);
    gemm_swz<true, false, false, unsigned short>
        <<<1024, 256, 0, stream>>>(bufH, 512, Wt + 2 * 262144, tmpT, 16384, nullptr);
    gemm_swz<false, true, false, float>
        <<<1024, 256, 0, stream>>>(tmpT, 16384, adjB, out, 512, b2);
}

// Round 6
// 231.500 us; speedup vs baseline: 6.0377x; 6.0377x over previous
//
#include <hip/hip_runtime.h>
#include <stdint.h>

// ---------- types ----------
typedef __bf16 bf16x8 __attribute__((ext_vector_type(8)));
typedef float f32x4 __attribute__((ext_vector_type(4)));
typedef unsigned short u16x4 __attribute__((ext_vector_type(4)));

static __device__ __forceinline__ unsigned short f2bf(float f) {
    union { float f; unsigned u; } v; v.f = f;
    unsigned r = (v.u + 0x7FFFu + ((v.u >> 16) & 1u)) >> 16;  // RNE
    return (unsigned short)r;
}

// ---------- fused prep: convert X, convert adj, transpose W0/W1/W2 ----------
__global__ void prep_kernel(const float* __restrict__ X,
                            const float* __restrict__ adj,
                            const float* __restrict__ W0,
                            const float* __restrict__ W1,
                            const float* __restrict__ W2,
                            unsigned short* __restrict__ bufH,
                            unsigned short* __restrict__ adjB,
                            unsigned short* __restrict__ Wt) {
    const int bid = blockIdx.x;
    const int t = threadIdx.x;
    if (bid < 16384) {
        const float* src = (bid < 8192) ? X : adj;
        unsigned short* dst = (bid < 8192) ? bufH : adjB;
        const int i = (bid & 8191) * 256 + t;
        f32x4 v = ((const f32x4*)src)[i];
        u16x4 o;
        o.x = f2bf(v.x); o.y = f2bf(v.y); o.z = f2bf(v.z); o.w = f2bf(v.w);
        ((u16x4*)dst)[i] = o;
    } else {
        const int wb = bid - 16384;          // 0..767
        const int z = wb >> 8;
        const int tile = wb & 255;
        const float* W = (z == 0) ? W0 : (z == 1) ? W1 : W2;
        unsigned short* dst = Wt + (size_t)z * (512 * 512);
        __shared__ float tileS[32][33];
        const int bx = (tile & 15) * 32, by = (tile >> 4) * 32;
        const int tx = t & 31, ty = t >> 5;  // 32 x 8
        #pragma unroll
        for (int r = 0; r < 32; r += 8)
            tileS[ty + r][tx] = W[(size_t)(by + ty + r) * 512 + (bx + tx)];
        __syncthreads();
        #pragma unroll
        for (int r = 0; r < 32; r += 8)
            dst[(size_t)(bx + ty + r) * 512 + (by + tx)] = f2bf(tileS[tx][ty + r]);
    }
}

// ---------- double-buffered GEMM tile ----------
// D[m][n] = sum_k A[m*LDA+k]*B[n*LDB+k]; writes out[n*LDO+m] (+bias[m], relu)
// 128x64 tile, BK=64, 256 threads (4 waves 2x2: 64m x 32n per wave).
// LDS: 2 buffers each for A (16KB) and B (8KB) = 48KB -> 3 blocks/CU.
// XOR swizzle: chunk(row,pos) at row*8 + (pos ^ (row&7)), 16B chunks.
// K-loop: 1 barrier/iter; loads for iter k+1 issued right after the barrier,
// so the next barrier's vmcnt(0) drain lands a full compute-phase after issue.
template<bool BIAS, bool RELU, typename OT>
__device__ __forceinline__
void gemm_tile(const unsigned short* __restrict__ A, int LDA,
               const unsigned short* __restrict__ B, int LDB,
               OT* __restrict__ out, int LDO,
               const float* __restrict__ bias,
               int m0, int n0,
               unsigned short* As, unsigned short* Bs) {
    const int tid  = threadIdx.x;
    const int lane = tid & 63;
    const int wave = tid >> 6;
    const int quad = lane >> 4;
    const int l16  = lane & 15;
    const int wm   = wave & 1;
    const int wn   = wave >> 1;

    const int srow = tid >> 3;                 // 0..31
    const int spos = (tid & 7) ^ (srow & 7);
    const unsigned short* aG = A + (size_t)(m0 + srow) * LDA + spos * 8;
    const unsigned short* bG = B + (size_t)(n0 + srow) * LDB + spos * 8;

    f32x4 acc[4][2];
    #pragma unroll
    for (int i = 0; i < 4; ++i)
        #pragma unroll
        for (int j = 0; j < 2; ++j) {
            f32x4 z = {0.f, 0.f, 0.f, 0.f};
            acc[i][j] = z;
        }

    // stage loads for K-tile kk into buffer buf
    auto issue = [&](int kk, int buf) {
        const int ko = kk * 64;
        char* aL = (char*)(As + buf * 8192) + tid * 16;
        char* bL = (char*)(Bs + buf * 4096) + tid * 16;
        #pragma unroll
        for (int r = 0; r < 4; ++r)
            __builtin_amdgcn_global_load_lds(
                (__attribute__((address_space(1))) void*)(uintptr_t)(aG + (size_t)(r * 32) * LDA + ko),
                (__attribute__((address_space(3))) void*)(aL + r * 4096), 16, 0, 0);
        #pragma unroll
        for (int r = 0; r < 2; ++r)
            __builtin_amdgcn_global_load_lds(
                (__attribute__((address_space(1))) void*)(uintptr_t)(bG + (size_t)(r * 32) * LDB + ko),
                (__attribute__((address_space(3))) void*)(bL + r * 4096), 16, 0, 0);
    };

    issue(0, 0);

    #pragma unroll 1
    for (int kk = 0; kk < 8; ++kk) {   // K=512, BK=64
        const int cur = kk & 1;
        __syncthreads();               // vmcnt(0): drains loads issued last iter
        if (kk < 7) issue(kk + 1, cur ^ 1);

        const unsigned short* Ab = As + cur * 8192;
        const unsigned short* Bb = Bs + cur * 4096;
        #pragma unroll
        for (int ks = 0; ks < 2; ++ks) {
            bf16x8 af[4], bfr[2];
            #pragma unroll
            for (int i = 0; i < 4; ++i) {
                const int row = wm * 64 + i * 16 + l16;
                const int idx = row * 8 + ((ks * 4 + quad) ^ (row & 7));
                af[i] = *(const bf16x8*)((const char*)Ab + idx * 16);
            }
            #pragma unroll
            for (int j = 0; j < 2; ++j) {
                const int row = wn * 32 + j * 16 + l16;
                const int idx = row * 8 + ((ks * 4 + quad) ^ (row & 7));
                bfr[j] = *(const bf16x8*)((const char*)Bb + idx * 16);
            }
            #pragma unroll
            for (int i = 0; i < 4; ++i)
                #pragma unroll
                for (int j = 0; j < 2; ++j)
                    acc[i][j] = __builtin_amdgcn_mfma_f32_16x16x32_bf16(af[i], bfr[j], acc[i][j], 0, 0, 0);
        }
    }

    // epilogue: C/D layout col=l16 (n-dim), row=quad*4+reg (m-dim); write out[n*LDO+m]
    #pragma unroll
    for (int i = 0; i < 4; ++i) {
        const int mb = m0 + wm * 64 + i * 16 + quad * 4;
        f32x4 bb = {0.f, 0.f, 0.f, 0.f};
        if constexpr (BIAS) bb = *(const f32x4*)(bias + mb);
        #pragma unroll
        for (int j = 0; j < 2; ++j) {
            const int n = n0 + wn * 32 + j * 16 + l16;
            f32x4 v = acc[i][j];
            if constexpr (BIAS) v += bb;
            if constexpr (RELU) {
                v.x = v.x > 0.f ? v.x : 0.f;
                v.y = v.y > 0.f ? v.y : 0.f;
                v.z = v.z > 0.f ? v.z : 0.f;
                v.w = v.w > 0.f ? v.w : 0.f;
            }
            if constexpr (sizeof(OT) == 4) {
                *(f32x4*)((float*)out + (size_t)n * LDO + mb) = v;
            } else {
                u16x4 o;
                o.x = f2bf(v.x); o.y = f2bf(v.y); o.z = f2bf(v.z); o.w = f2bf(v.w);
                *(u16x4*)((unsigned short*)out + (size_t)n * LDO + mb) = o;
            }
        }
    }
}

// ---- XCD-swizzled tile decode (blockIdx -> XCD is round-robin, bid % 8) ----
// Feature phase (1024 tiles = 128 m x 8 n): XCD k owns m-tiles [16k,16k+16).
__device__ __forceinline__ void feat_tile(int b, int& m0, int& n0) {
    const int xcd = b & 7, s = b >> 3;         // s in [0,128)
    m0 = (xcd * 16 + (s >> 3)) * 128;
    n0 = (s & 7) * 64;
}
// Aggregate phase (1024 tiles = 32 z x 4 m x 8 n): XCD k owns graphs {k,k+8,k+16,k+24}.
__device__ __forceinline__ void aggr_tile(int b, int& z, int& m0, int& n0) {
    const int xcd = b & 7, s = b >> 3;         // s in [0,128)
    z = xcd + 8 * (s >> 5);
    const int inner = s & 31;
    m0 = (inner >> 3) * 128;
    n0 = (inner & 7) * 64;
}

template<bool FEAT, bool BIAS, bool RELU, typename OT>
__global__ __launch_bounds__(256, 3)
void gemm_swz(const unsigned short* __restrict__ A, int LDA,
              const unsigned short* __restrict__ B,
              OT* __restrict__ out, int LDO,
              const float* __restrict__ bias) {
    __shared__ unsigned short As[2 * 128 * 64];   // 32 KB
    __shared__ unsigned short Bs[2 * 64 * 64];    // 16 KB
    int z, m0, n0;
    if constexpr (FEAT) {
        feat_tile(blockIdx.x, m0, n0);
        gemm_tile<BIAS, RELU, OT>(A, LDA, B, 512, out, LDO, bias, m0, n0, As, Bs);
    } else {
        aggr_tile(blockIdx.x, z, m0, n0);
        gemm_tile<BIAS, RELU, OT>(A + z * 512, LDA, B + (size_t)z * 262144, 512,
                                  out + (size_t)z * 262144, LDO, bias, m0, n0, As, Bs);
    }
}

extern "C" void kernel_launch(void* const* d_in, const int* in_sizes, int n_in,
                              void* d_out, int out_size, void* d_ws, size_t ws_size,
                              hipStream_t stream) {
    (void)in_sizes; (void)n_in; (void)out_size; (void)ws_size;
    const float* X   = (const float*)d_in[0];
    const float* adj = (const float*)d_in[1];
    const float* W0  = (const float*)d_in[2];
    const float* b0  = (const float*)d_in[3];
    const float* W1  = (const float*)d_in[4];
    const float* b1  = (const float*)d_in[5];
    const float* W2  = (const float*)d_in[6];
    const float* b2  = (const float*)d_in[7];
    float* out = (float*)d_out;

    // workspace (bf16): adjB | bufH (X/h, node-major) | tmpT (feat-major) | Wt x3
    char* ws = (char*)d_ws;
    const size_t SZ = 16777216;  // 32*512*512*2
    unsigned short* adjB = (unsigned short*)(ws);
    unsigned short* bufH = (unsigned short*)(ws + SZ);
    unsigned short* tmpT = (unsigned short*)(ws + 2 * SZ);
    unsigned short* Wt   = (unsigned short*)(ws + 3 * SZ);

    prep_kernel<<<16384 + 768, 256, 0, stream>>>(X, adj, W0, W1, W2, bufH, adjB, Wt);

    // layer 0
    gemm_swz<true, false, false, unsigned short>
        <<<1024, 256, 0, stream>>>(bufH, 512, Wt, tmpT, 16384, nullptr);
    gemm_swz<false, true, true, unsigned short>
        <<<1024, 256, 0, stream>>>(tmpT, 16384, adjB, bufH, 512, b0);
    // layer 1
    gemm_swz<true, false, false, unsigned short>
        <<<1024, 256, 0, stream>>>(bufH, 512, Wt + 262144, tmpT, 16384, nullptr);
    gemm_swz<false, true, true, unsigned short>
        <<<1024, 256, 0, stream>>>(tmpT, 16384, adjB, bufH, 512, b1);
    // layer 2 (no relu, fp32 out)
    gemm_swz<true, false, false, unsigned short>
        <<<1024, 256, 0, stream>>>(bufH, 512, Wt + 2 * 262144, tmpT, 16384, nullptr);
    gemm_swz<false, true, false, float>
        <<<1024, 256, 0, stream>>>(tmpT, 16384, adjB, out, 512, b2);
}

// Round 7
// 229.130 us; speedup vs baseline: 6.1001x; 1.0103x over previous
//
#include <hip/hip_runtime.h>
#include <stdint.h>

#define AS1 __attribute__((address_space(1)))
#define AS3 __attribute__((address_space(3)))

// ---------- types ----------
typedef __bf16 bf16x8 __attribute__((ext_vector_type(8)));
typedef float f32x4 __attribute__((ext_vector_type(4)));
typedef unsigned short u16x4 __attribute__((ext_vector_type(4)));

static __device__ __forceinline__ unsigned short f2bf(float f) {
    union { float f; unsigned u; } v; v.f = f;
    unsigned r = (v.u + 0x7FFFu + ((v.u >> 16) & 1u)) >> 16;  // RNE
    return (unsigned short)r;
}

// ---------- fused prep: convert X, convert adj, transpose W0/W1/W2 ----------
__global__ void prep_kernel(const float* __restrict__ X,
                            const float* __restrict__ adj,
                            const float* __restrict__ W0,
                            const float* __restrict__ W1,
                            const float* __restrict__ W2,
                            unsigned short* __restrict__ bufH,
                            unsigned short* __restrict__ adjB,
                            unsigned short* __restrict__ Wt) {
    const int bid = blockIdx.x;
    const int t = threadIdx.x;
    if (bid < 16384) {
        const float* src = (bid < 8192) ? X : adj;
        unsigned short* dst = (bid < 8192) ? bufH : adjB;
        const int i = (bid & 8191) * 256 + t;
        f32x4 v = ((const f32x4*)src)[i];
        u16x4 o;
        o.x = f2bf(v.x); o.y = f2bf(v.y); o.z = f2bf(v.z); o.w = f2bf(v.w);
        ((u16x4*)dst)[i] = o;
    } else {
        const int wb = bid - 16384;          // 0..767
        const int z = wb >> 8;
        const int tile = wb & 255;
        const float* W = (z == 0) ? W0 : (z == 1) ? W1 : W2;
        unsigned short* dst = Wt + (size_t)z * (512 * 512);
        __shared__ float tileS[32][33];
        const int bx = (tile & 15) * 32, by = (tile >> 4) * 32;
        const int tx = t & 31, ty = t >> 5;  // 32 x 8
        #pragma unroll
        for (int r = 0; r < 32; r += 8)
            tileS[ty + r][tx] = W[(size_t)(by + ty + r) * 512 + (bx + tx)];
        __syncthreads();
        #pragma unroll
        for (int r = 0; r < 32; r += 8)
            dst[(size_t)(bx + ty + r) * 512 + (by + tx)] = f2bf(tileS[tx][ty + r]);
    }
}

// ---------- fused GCN layer: out_g = [relu](adj_g @ (h_g @ W) + b) ----------
// Block = (graph g, 64-wide e-tile). 512 threads = 8 waves; wave w owns nodes
// [w*64, w*64+64).
// Phase A: S^T[e][m] = sum_k W^T[e0+e][k] * h_g[m][k]   (A-frags from LDS W^T,
//          B-frags direct-global h).
// S^T then overwrites the (dead) W^T LDS region in the SAME swizzled layout.
// Phase B: out[n][e0+e] = sum_m S^T[e][m] * adj_g[n][m] (A-frags from LDS S^T,
//          B-frags direct-global adj).
// LDS layout: 16 k-blocks (32 k each) x [64 rows x 4 chunks x 16B]; chunk slot
// = row*4 + (pos ^ (row&3)). 64 KB total. 3 barriers per layer, no per-K-iter
// barrier; direct-global fragment loads get fine-grained vmcnt from compiler.
template<bool RELU, typename OT>
__global__ __launch_bounds__(512, 1)
void gcn_layer(const unsigned short* __restrict__ hin,
               const unsigned short* __restrict__ adjB,
               const unsigned short* __restrict__ WtL,
               const float* __restrict__ bias,
               OT* __restrict__ hout) {
    __shared__ unsigned short AM[32768];   // 64 KB

    const int bid = blockIdx.x;
    const int s = bid >> 3;
    const int g = (bid & 7) + 8 * (s >> 3);   // all 8 e-tiles of graph g share an XCD
    const int e0 = (s & 7) * 64;

    const unsigned short* __restrict__ h_g = hin + (size_t)g * 262144;
    const unsigned short* __restrict__ a_g = adjB + (size_t)g * 262144;

    const int tid  = threadIdx.x;
    const int lane = tid & 63;
    const int w    = tid >> 6;
    const int quad = lane >> 4;
    const int l16  = lane & 15;
    const int n0w  = w * 64;

    // ---- stage W^T e-slice (64 rows x 512 k) into AM ----
    {
        const int row = (tid & 255) >> 2;
        const int pos = (tid & 3) ^ ((tid >> 2) & 3);
        const unsigned short* gsrc =
            WtL + (size_t)(e0 + row) * 512 + (tid >> 8) * 32 + pos * 8;
        char* ldst = (char*)AM + tid * 16;
        #pragma unroll
        for (int r = 0; r < 8; ++r)
            __builtin_amdgcn_global_load_lds(
                (AS1 void*)(uintptr_t)(gsrc + r * 64),
                (AS3 void*)(ldst + r * 8192), 16, 0, 0);
    }
    __syncthreads();

    // ---- phase A ----
    f32x4 acc[4][4];
    #pragma unroll
    for (int i = 0; i < 4; ++i)
        #pragma unroll
        for (int j = 0; j < 4; ++j) {
            f32x4 z = {0.f, 0.f, 0.f, 0.f};
            acc[i][j] = z;
        }

    #pragma unroll
    for (int kb = 0; kb < 16; ++kb) {
        bf16x8 af[4], bf[4];
        #pragma unroll
        for (int i = 0; i < 4; ++i) {
            const int row = i * 16 + l16;
            af[i] = *(const bf16x8*)((char*)AM + kb * 4096 +
                                     (row * 4 + (quad ^ (row & 3))) * 16);
        }
        #pragma unroll
        for (int j = 0; j < 4; ++j)
            bf[j] = *(const bf16x8*)(h_g + (size_t)(n0w + j * 16 + l16) * 512 +
                                     kb * 32 + quad * 8);
        #pragma unroll
        for (int i = 0; i < 4; ++i)
            #pragma unroll
            for (int j = 0; j < 4; ++j)
                acc[i][j] = __builtin_amdgcn_mfma_f32_16x16x32_bf16(af[i], bf[j], acc[i][j], 0, 0, 0);
    }
    __syncthreads();   // all waves done reading W^T

    // ---- write S^T into AM (overwrite W^T), same swizzled layout ----
    // acc layout: col(n'=node m) = l16, row(m'=e) = quad*4 + r
    #pragma unroll
    for (int i = 0; i < 4; ++i)
        #pragma unroll
        for (int j = 0; j < 4; ++j) {
            const int m = n0w + j * 16 + l16;
            const int mb = m >> 5;
            const int q = (m >> 3) & 3;
            const int elem = m & 7;
            #pragma unroll
            for (int r = 0; r < 4; ++r) {
                const int e = i * 16 + quad * 4 + r;
                *((unsigned short*)((char*)AM + mb * 4096 +
                                    (e * 4 + (q ^ (e & 3))) * 16) + elem)
                    = f2bf(acc[i][j][r]);
            }
        }
    __syncthreads();

    // ---- phase B ----
    f32x4 acc2[4][4];
    #pragma unroll
    for (int i = 0; i < 4; ++i)
        #pragma unroll
        for (int j = 0; j < 4; ++j) {
            f32x4 z = {0.f, 0.f, 0.f, 0.f};
            acc2[i][j] = z;
        }

    #pragma unroll
    for (int mb = 0; mb < 16; ++mb) {
        bf16x8 af[4], bf[4];
        #pragma unroll
        for (int i = 0; i < 4; ++i) {
            const int row = i * 16 + l16;
            af[i] = *(const bf16x8*)((char*)AM + mb * 4096 +
                                     (row * 4 + (quad ^ (row & 3))) * 16);
        }
        #pragma unroll
        for (int j = 0; j < 4; ++j)
            bf[j] = *(const bf16x8*)(a_g + (size_t)(n0w + j * 16 + l16) * 512 +
                                     mb * 32 + quad * 8);
        #pragma unroll
        for (int i = 0; i < 4; ++i)
            #pragma unroll
            for (int j = 0; j < 4; ++j)
                acc2[i][j] = __builtin_amdgcn_mfma_f32_16x16x32_bf16(af[i], bf[j], acc2[i][j], 0, 0, 0);
    }

    // ---- epilogue: out_g[n][e0+e] = acc2 + b[e], optional relu ----
    #pragma unroll
    for (int i = 0; i < 4; ++i) {
        const int e = e0 + i * 16 + quad * 4;
        const f32x4 bb = *(const f32x4*)(bias + e);
        #pragma unroll
        for (int j = 0; j < 4; ++j) {
            const int n = n0w + j * 16 + l16;
            f32x4 v = acc2[i][j] + bb;
            if constexpr (RELU) {
                v.x = v.x > 0.f ? v.x : 0.f;
                v.y = v.y > 0.f ? v.y : 0.f;
                v.z = v.z > 0.f ? v.z : 0.f;
                v.w = v.w > 0.f ? v.w : 0.f;
            }
            if constexpr (sizeof(OT) == 4) {
                *(f32x4*)((float*)hout + (size_t)g * 262144 + (size_t)n * 512 + e) = v;
            } else {
                u16x4 o;
                o.x = f2bf(v.x); o.y = f2bf(v.y); o.z = f2bf(v.z); o.w = f2bf(v.w);
                *(u16x4*)((unsigned short*)hout + (size_t)g * 262144 + (size_t)n * 512 + e) = o;
            }
        }
    }
}

extern "C" void kernel_launch(void* const* d_in, const int* in_sizes, int n_in,
                              void* d_out, int out_size, void* d_ws, size_t ws_size,
                              hipStream_t stream) {
    (void)in_sizes; (void)n_in; (void)out_size; (void)ws_size;
    const float* X   = (const float*)d_in[0];
    const float* adj = (const float*)d_in[1];
    const float* W0  = (const float*)d_in[2];
    const float* b0  = (const float*)d_in[3];
    const float* W1  = (const float*)d_in[4];
    const float* b1  = (const float*)d_in[5];
    const float* W2  = (const float*)d_in[6];
    const float* b2  = (const float*)d_in[7];
    float* out = (float*)d_out;

    // workspace (bf16): adjB | bufH | bufH2 | Wt x3
    char* ws = (char*)d_ws;
    const size_t SZ = 16777216;  // 32*512*512*2
    unsigned short* adjB  = (unsigned short*)(ws);
    unsigned short* bufH  = (unsigned short*)(ws + SZ);
    unsigned short* bufH2 = (unsigned short*)(ws + 2 * SZ);
    unsigned short* Wt    = (unsigned short*)(ws + 3 * SZ);

    prep_kernel<<<16384 + 768, 256, 0, stream>>>(X, adj, W0, W1, W2, bufH, adjB, Wt);

    gcn_layer<true, unsigned short>
        <<<256, 512, 0, stream>>>(bufH, adjB, Wt, b0, bufH2);
    gcn_layer<true, unsigned short>
        <<<256, 512, 0, stream>>>(bufH2, adjB, Wt + 262144, b1, bufH);
    gcn_layer<false, float>
        <<<256, 512, 0, stream>>>(bufH, adjB, Wt + 2 * 262144, b2, out);
}